// Round 14
// baseline (281.194 us; speedup 1.0000x reference)
//
#include <hip/hip_runtime.h>

#define NTEST  16384
#define NTRAIN 8192
#define DIM    64
#define NCOLSPLIT 16
#define WPB    8                            // waves per block (512 threads)

typedef _Float16 f16x8  __attribute__((ext_vector_type(8)));
typedef float    f32x16 __attribute__((ext_vector_type(16)));

#define LOG2E 1.4426950408889634f

// One wave per row. Rows [0,NTEST) = test_X -> A_hi (row-major) + nx2=cn*nx.
// Rows [NTEST,..) = train_X -> B_hi in TILE-MAJOR fragment layout +
// wt = alpha * exp2(cn*nt)  (train-norm folded into the weight).
// hi-only f16 (calibrated: 4x margin, rounds 9-13 measured 1.455e-11).
// Tile-major: for train row r, dim k:
//   flat = (r>>5)*2048 + (k>>4)*512 + (((k>>3)&1)*32 + (r&31))*8 + (k&7)
__global__ __launch_bounds__(256) void krr_prep(
    const float* __restrict__ test_X, const float* __restrict__ train_X,
    const float* __restrict__ alphas, const float* __restrict__ lengthscale,
    _Float16* __restrict__ A_hi, _Float16* __restrict__ B_hi,
    float* __restrict__ nx2, float* __restrict__ wt)
{
    int gwave = (blockIdx.x * 256 + threadIdx.x) >> 6;
    int lane  = threadIdx.x & 63;           // = dim index k
    bool is_test = gwave < NTEST;
    int row = is_test ? gwave : gwave - NTEST;
    const float* src = is_test ? test_X : train_X;

    float x = src[(size_t)row * DIM + lane];
    _Float16 h = (_Float16)x;                // RNE to f16

    if (is_test) {
        A_hi[(size_t)row * DIM + lane] = h;
    } else {
        int t  = row >> 5, lr = row & 31;
        int kk = lane >> 4, hi = (lane >> 3) & 1, e = lane & 7;
        size_t dst = (size_t)t * 2048 + (size_t)kk * 512 + (size_t)(hi * 32 + lr) * 8 + e;
        B_hi[dst] = h;
    }

    float s = x * x;
    s += __shfl_xor(s, 1);  s += __shfl_xor(s, 2);  s += __shfl_xor(s, 4);
    s += __shfl_xor(s, 8);  s += __shfl_xor(s, 16); s += __shfl_xor(s, 32);
    if (lane == 0) {
        float ls   = lengthscale[0];
        float inv2 = 1.0f / (ls * ls);
        float cn   = -0.5f * inv2 * LOG2E;   // log2-domain norm coefficient
        if (is_test) nx2[row] = s * cn;
        else         wt[row]  = alphas[row] * __builtin_amdgcn_exp2f(cn * s);
    }
}

// LDS-STAGED: rounds 9-13 showed pipe-times SUMMING to dur (no overlap) —
// every B fragment + wt came from L2 (~250 cyc) as a per-wave dependent
// chain. Fix: WG = 8 waves x 256 test rows x ONE 512-col strip; the strip's
// B (64KB) is staged through a 32KB LDS buffer in 2 phases (+2KB wt), so the
// 16-tile compute loop has ZERO global loads. 34KB LDS -> 4 WG/CU (full
// 2048-thread residency). 3 barriers total. Per-wave math/epilogue identical
// to round 13 (2-tile ILP, compile-time indices only — rule #20).
// K*alpha = exp2(s1*C + nx2[row]) * wt[col].
__global__ __launch_bounds__(512) void krr_mfma(
    const _Float16* __restrict__ A_hi, const _Float16* __restrict__ B_hi,
    const float* __restrict__ nx2, const float* __restrict__ wt,
    const float* __restrict__ lengthscale, float* __restrict__ out)
{
    alignas(16) __shared__ _Float16 Bs[8 * 2048];   // 8 tiles = 32 KB
    __shared__ float wts[512];                      // 2 KB

    const int tid   = threadIdx.x;
    const int lane  = tid & 63;
    const int wave  = tid >> 6;
    const int rbase = blockIdx.x * 256 + wave * 32;
    const int cb    = blockIdx.y;                   // col-split index

    const float ls   = lengthscale[0];
    const float inv2 = 1.0f / (ls * ls);
    const float s1   = inv2 * LOG2E;         // dot coefficient (log2 domain)

    // Stage the strip's weights once (512 threads x 4B).
    wts[tid] = wt[cb * 512 + tid];

    const int arow = rbase + (lane & 31);
    const int koff = (lane >> 5) * 8;        // canonical k-map, same for A and B

    // A fragments, loop-invariant: 4 x 16B = 16 VGPRs
    f16x8 ah[4];
    #pragma unroll
    for (int kk = 0; kk < 4; ++kk)
        ah[kk] = *reinterpret_cast<const f16x8*>(A_hi + (size_t)arow * DIM + kk * 16 + koff);

    // per-lane row constants: cn*nx for the 16 C/D rows this lane holds
    float nxc[16];
    #pragma unroll
    for (int r = 0; r < 16; ++r) {
        int row = (r & 3) + 8 * (r >> 2) + 4 * (lane >> 5);
        nxc[r] = nx2[rbase + row];
    }

    float acc[16];
    #pragma unroll
    for (int r = 0; r < 16; ++r) acc[r] = 0.0f;

    #pragma unroll
    for (int p = 0; p < 2; ++p) {
        if (p) __syncthreads();   // all waves done reading phase-0 Bs

        // Stage 8 tiles (32KB): 64B per thread, coalesced 16B chunks.
        {
            const _Float16* gsrc = B_hi + ((size_t)cb * 16 + p * 8) * 2048 + (size_t)tid * 32;
            float4 s0 = *reinterpret_cast<const float4*>(gsrc);
            float4 s1v = *reinterpret_cast<const float4*>(gsrc + 8);
            float4 s2 = *reinterpret_cast<const float4*>(gsrc + 16);
            float4 s3 = *reinterpret_cast<const float4*>(gsrc + 24);
            float4* dst = reinterpret_cast<float4*>(&Bs[(size_t)tid * 32]);
            dst[0] = s0; dst[1] = s1v; dst[2] = s2; dst[3] = s3;
        }
        __syncthreads();

        // Compute 8 tiles from LDS, two at a time (independent chains).
        for (int lt = 0; lt < 8; lt += 2) {
            const _Float16* pA = &Bs[(size_t)lt * 2048 + (size_t)lane * 8];
            const _Float16* pB = pA + 2048;
            f16x8 bhA[4], bhB[4];
            #pragma unroll
            for (int kk = 0; kk < 4; ++kk) {
                bhA[kk] = *reinterpret_cast<const f16x8*>(pA + kk * 512);
                bhB[kk] = *reinterpret_cast<const f16x8*>(pB + kk * 512);
            }
            const int wtb = (p * 8 + lt) * 32 + (lane & 31);
            const float wA = wts[wtb];
            const float wB = wts[wtb + 32];

            f32x16 CA = {};
            f32x16 CB = {};
            #pragma unroll
            for (int kk = 0; kk < 4; ++kk) {
                CA = __builtin_amdgcn_mfma_f32_32x32x16_f16(ah[kk], bhA[kk], CA, 0, 0, 0);
                CB = __builtin_amdgcn_mfma_f32_32x32x16_f16(ah[kk], bhB[kk], CB, 0, 0, 0);
            }

            #pragma unroll
            for (int r = 0; r < 16; ++r) {
                float argA = fmaf(CA[r], s1, nxc[r]);    // log2 domain
                float argB = fmaf(CB[r], s1, nxc[r]);
                acc[r] = fmaf(__builtin_amdgcn_exp2f(argA), wA, acc[r]);
                acc[r] = fmaf(__builtin_amdgcn_exp2f(argB), wB, acc[r]);
            }
        }
    }

    // Sum over the 32 train cols held across lanes of the same half.
    #pragma unroll
    for (int r = 0; r < 16; ++r) {
        float v = acc[r];
        v += __shfl_xor(v, 1);  v += __shfl_xor(v, 2);  v += __shfl_xor(v, 4);
        v += __shfl_xor(v, 8);  v += __shfl_xor(v, 16);
        if ((lane & 31) == 0) {
            int row = (r & 3) + 8 * (r >> 2) + 4 * (lane >> 5);
            atomicAdd(&out[rbase + row], v);
        }
    }
}

// ---------------- fallback (round-1 kernel, known-good) ----------------
#define TCHUNK 512
#define NCHUNK (NTRAIN / TCHUNK)
__global__ __launch_bounds__(256, 4) void krr_main(
    const float* __restrict__ test_X, const float* __restrict__ train_X,
    const float* __restrict__ alphas, const float* __restrict__ lengthscale,
    float* __restrict__ out)
{
    __shared__ float nt_lds[TCHUNK];
    __shared__ float al_lds[TCHUNK];
    const int tid = threadIdx.x;
    const int i   = blockIdx.x * 256 + tid;
    const int j0  = blockIdx.y * TCHUNK;
    const float ls   = lengthscale[0];
    const float inv2 = 1.0f / (ls * ls);
    for (int jj = tid; jj < TCHUNK; jj += 256) {
        const float4* tr = reinterpret_cast<const float4*>(train_X + (size_t)(j0 + jj) * DIM);
        float s = 0.f;
        #pragma unroll
        for (int k = 0; k < DIM / 4; ++k) {
            float4 t = tr[k];
            s += t.x * t.x + t.y * t.y + t.z * t.z + t.w * t.w;
        }
        nt_lds[jj] = s * inv2;
        al_lds[jj] = alphas[j0 + jj];
    }
    __syncthreads();
    float xr[DIM]; float nxv = 0.f;
    {
        const float4* xp = reinterpret_cast<const float4*>(test_X + (size_t)i * DIM);
        #pragma unroll
        for (int k = 0; k < DIM / 4; ++k) {
            float4 v = xp[k];
            xr[4*k+0] = v.x; xr[4*k+1] = v.y; xr[4*k+2] = v.z; xr[4*k+3] = v.w;
            nxv += v.x*v.x + v.y*v.y + v.z*v.z + v.w*v.w;
        }
        nxv *= inv2;
        #pragma unroll
        for (int k = 0; k < DIM; ++k) xr[k] *= inv2;
    }
    float acc = 0.f;
    for (int jj = 0; jj < TCHUNK; ++jj) {
        const float* trow = train_X + (size_t)(j0 + jj) * DIM;
        float d0 = 0.f, d1 = 0.f, d2 = 0.f, d3 = 0.f;
        #pragma unroll
        for (int k4 = 0; k4 < DIM / 4; ++k4) {
            float4 t = reinterpret_cast<const float4*>(trow)[k4];
            d0 = fmaf(xr[4*k4+0], t.x, d0);
            d1 = fmaf(xr[4*k4+1], t.y, d1);
            d2 = fmaf(xr[4*k4+2], t.z, d2);
            d3 = fmaf(xr[4*k4+3], t.w, d3);
        }
        float dot = (d0 + d1) + (d2 + d3);
        float sq  = nxv + nt_lds[jj] - 2.0f * dot;
        sq = fmaxf(sq, 0.0f);
        acc = fmaf(__expf(-0.5f * sq), al_lds[jj], acc);
    }
    atomicAdd(&out[i], acc);
}

extern "C" void kernel_launch(void* const* d_in, const int* in_sizes, int n_in,
                              void* d_out, int out_size, void* d_ws, size_t ws_size,
                              hipStream_t stream) {
    const float* test_X      = (const float*)d_in[0];
    const float* train_X     = (const float*)d_in[1];
    const float* alphas      = (const float*)d_in[2];
    const float* lengthscale = (const float*)d_in[3];
    float* out = (float*)d_out;

    hipMemsetAsync(out, 0, NTEST * sizeof(float), stream);

    const size_t need = (size_t)(NTEST + NTRAIN) * DIM * sizeof(_Float16)
                      + (NTEST + NTRAIN) * sizeof(float);
    if (ws_size >= need) {
        _Float16* A_hi = (_Float16*)d_ws;
        _Float16* B_hi = A_hi + (size_t)NTEST * DIM;
        float*    nx2  = (float*)(B_hi + (size_t)NTRAIN * DIM);
        float*    wtp  = nx2 + NTEST;

        krr_prep<<<(NTEST + NTRAIN) / 4, 256, 0, stream>>>(
            test_X, train_X, alphas, lengthscale, A_hi, B_hi, nx2, wtp);

        dim3 grid(NTEST / 256, NCOLSPLIT);
        krr_mfma<<<grid, 64 * WPB, 0, stream>>>(A_hi, B_hi, nx2, wtp,
                                                lengthscale, out);
    } else {
        dim3 grid(NTEST / 256, NCHUNK);
        krr_main<<<grid, 256, 0, stream>>>(test_X, train_X, alphas, lengthscale, out);
    }
}

// Round 15
// 45.518 us; speedup vs baseline: 6.1777x; 6.1777x over previous
//
#include <hip/hip_runtime.h>

#define NTEST  16384
#define NTRAIN 8192
#define DIM    64
#define NCOLSPLIT 16
#define WPB    8                            // waves per block (512 threads)

typedef _Float16 f16x8  __attribute__((ext_vector_type(8)));
typedef float    f32x16 __attribute__((ext_vector_type(16)));

#define LOG2E 1.4426950408889634f

// Direct global->LDS DMA: no staging VGPRs (r14's spill vector), linear
// wave-contiguous LDS writes (no ds_write bank conflicts). size must be a
// literal 16; LDS base wave-uniform, +lane*16 implicit.
#define GLOAD_LDS16(gsrc, ldst)                                                     \
    __builtin_amdgcn_global_load_lds(                                               \
        (const __attribute__((address_space(1))) unsigned int*)(gsrc),              \
        (__attribute__((address_space(3))) unsigned int*)(ldst), 16, 0, 0)

// One wave per row. Rows [0,NTEST) = test_X -> A_hi (row-major) + nx2=cn*nx.
// Rows [NTEST,..) = train_X -> B_hi in TILE-MAJOR fragment layout +
// wt = alpha * exp2(cn*nt)  (train-norm folded into the weight).
// hi-only f16 (calibrated: 4x margin, rounds 9-14 measured 1.455e-11).
// Tile-major: for train row r, dim k:
//   flat = (r>>5)*2048 + (k>>4)*512 + (((k>>3)&1)*32 + (r&31))*8 + (k&7)
__global__ __launch_bounds__(256) void krr_prep(
    const float* __restrict__ test_X, const float* __restrict__ train_X,
    const float* __restrict__ alphas, const float* __restrict__ lengthscale,
    _Float16* __restrict__ A_hi, _Float16* __restrict__ B_hi,
    float* __restrict__ nx2, float* __restrict__ wt)
{
    int gwave = (blockIdx.x * 256 + threadIdx.x) >> 6;
    int lane  = threadIdx.x & 63;           // = dim index k
    bool is_test = gwave < NTEST;
    int row = is_test ? gwave : gwave - NTEST;
    const float* src = is_test ? test_X : train_X;

    float x = src[(size_t)row * DIM + lane];
    _Float16 h = (_Float16)x;                // RNE to f16

    if (is_test) {
        A_hi[(size_t)row * DIM + lane] = h;
    } else {
        int t  = row >> 5, lr = row & 31;
        int kk = lane >> 4, hi = (lane >> 3) & 1, e = lane & 7;
        size_t dst = (size_t)t * 2048 + (size_t)kk * 512 + (size_t)(hi * 32 + lr) * 8 + e;
        B_hi[dst] = h;
    }

    float s = x * x;
    s += __shfl_xor(s, 1);  s += __shfl_xor(s, 2);  s += __shfl_xor(s, 4);
    s += __shfl_xor(s, 8);  s += __shfl_xor(s, 16); s += __shfl_xor(s, 32);
    if (lane == 0) {
        float ls   = lengthscale[0];
        float inv2 = 1.0f / (ls * ls);
        float cn   = -0.5f * inv2 * LOG2E;   // log2-domain norm coefficient
        if (is_test) nx2[row] = s * cn;
        else         wt[row]  = alphas[row] * __builtin_amdgcn_exp2f(cn * s);
    }
}

// LDS-staged via global_load_lds. WG = 8 waves x 256 test rows x ONE
// 512-col strip; B staged 32KB/phase (2 phases), wave w DMAs tile (p*8+w)
// with 4x global_load_lds (1KB each, zero data registers). Compute loop has
// zero global loads: conflict-free ds_read_b128 fragments + broadcast wt.
// r14 lessons encoded: no reg-staging (spill), no 64B-stride ds_write
// (16-way conflict), '#pragma unroll 1' pins the tile loop at the r13
// register budget (52 VGPR). Per-wave math identical to r13 (2-tile ILP).
// K*alpha = exp2(s1*C + nx2[row]) * wt[col].
__global__ __launch_bounds__(512) void krr_mfma(
    const _Float16* __restrict__ A_hi, const _Float16* __restrict__ B_hi,
    const float* __restrict__ nx2, const float* __restrict__ wt,
    const float* __restrict__ lengthscale, float* __restrict__ out)
{
    alignas(16) __shared__ _Float16 Bs[8 * 2048];   // 8 tiles = 32 KB
    __shared__ float wts[512];                      // 2 KB

    const int tid   = threadIdx.x;
    const int lane  = tid & 63;
    const int wave  = tid >> 6;
    const int rbase = blockIdx.x * 256 + wave * 32;
    const int cb    = blockIdx.y;                   // col-split index

    const float ls   = lengthscale[0];
    const float inv2 = 1.0f / (ls * ls);
    const float s1   = inv2 * LOG2E;         // dot coefficient (log2 domain)

    // Stage the strip's weights once (512 threads x 4B, conflict-free).
    wts[tid] = wt[cb * 512 + tid];

    const int arow = rbase + (lane & 31);
    const int koff = (lane >> 5) * 8;        // canonical k-map, same for A and B

    // A fragments, loop-invariant: 4 x 16B = 16 VGPRs
    f16x8 ah[4];
    #pragma unroll
    for (int kk = 0; kk < 4; ++kk)
        ah[kk] = *reinterpret_cast<const f16x8*>(A_hi + (size_t)arow * DIM + kk * 16 + koff);

    // per-lane row constants: cn*nx for the 16 C/D rows this lane holds
    float nxc[16];
    #pragma unroll
    for (int r = 0; r < 16; ++r) {
        int row = (r & 3) + 8 * (r >> 2) + 4 * (lane >> 5);
        nxc[r] = nx2[rbase + row];
    }

    float acc[16];
    #pragma unroll
    for (int r = 0; r < 16; ++r) acc[r] = 0.0f;

    for (int p = 0; p < 2; ++p) {
        if (p) __syncthreads();   // all waves done reading phase-0 Bs

        // Wave w DMAs tile (p*8 + w): 4 x 1KB global_load_lds.
        {
            const _Float16* gt = B_hi + ((size_t)cb * 16 + p * 8 + wave) * 2048
                               + (size_t)lane * 8;
            _Float16* lt0 = &Bs[(size_t)wave * 2048];
            GLOAD_LDS16(gt,        lt0);
            GLOAD_LDS16(gt + 512,  lt0 + 512);
            GLOAD_LDS16(gt + 1024, lt0 + 1024);
            GLOAD_LDS16(gt + 1536, lt0 + 1536);
        }
        __syncthreads();          // drains vmcnt (global_load_lds) + orders LDS

        // Compute 8 tiles from LDS, two at a time (independent chains).
        #pragma unroll 1
        for (int lt = 0; lt < 8; lt += 2) {
            const _Float16* pA = &Bs[(size_t)lt * 2048 + (size_t)lane * 8];
            const _Float16* pB = pA + 2048;
            f16x8 bhA[4], bhB[4];
            #pragma unroll
            for (int kk = 0; kk < 4; ++kk) {
                bhA[kk] = *reinterpret_cast<const f16x8*>(pA + kk * 512);
                bhB[kk] = *reinterpret_cast<const f16x8*>(pB + kk * 512);
            }
            const int wtb = (p * 8 + lt) * 32 + (lane & 31);
            const float wA = wts[wtb];
            const float wB = wts[wtb + 32];

            f32x16 CA = {};
            f32x16 CB = {};
            #pragma unroll
            for (int kk = 0; kk < 4; ++kk) {
                CA = __builtin_amdgcn_mfma_f32_32x32x16_f16(ah[kk], bhA[kk], CA, 0, 0, 0);
                CB = __builtin_amdgcn_mfma_f32_32x32x16_f16(ah[kk], bhB[kk], CB, 0, 0, 0);
            }

            #pragma unroll
            for (int r = 0; r < 16; ++r) {
                float argA = fmaf(CA[r], s1, nxc[r]);    // log2 domain
                float argB = fmaf(CB[r], s1, nxc[r]);
                acc[r] = fmaf(__builtin_amdgcn_exp2f(argA), wA, acc[r]);
                acc[r] = fmaf(__builtin_amdgcn_exp2f(argB), wB, acc[r]);
            }
        }
    }

    // Sum over the 32 train cols held across lanes of the same half.
    #pragma unroll
    for (int r = 0; r < 16; ++r) {
        float v = acc[r];
        v += __shfl_xor(v, 1);  v += __shfl_xor(v, 2);  v += __shfl_xor(v, 4);
        v += __shfl_xor(v, 8);  v += __shfl_xor(v, 16);
        if ((lane & 31) == 0) {
            int row = (r & 3) + 8 * (r >> 2) + 4 * (lane >> 5);
            atomicAdd(&out[rbase + row], v);
        }
    }
}

// ---------------- fallback (round-1 kernel, known-good) ----------------
#define TCHUNK 512
#define NCHUNK (NTRAIN / TCHUNK)
__global__ __launch_bounds__(256, 4) void krr_main(
    const float* __restrict__ test_X, const float* __restrict__ train_X,
    const float* __restrict__ alphas, const float* __restrict__ lengthscale,
    float* __restrict__ out)
{
    __shared__ float nt_lds[TCHUNK];
    __shared__ float al_lds[TCHUNK];
    const int tid = threadIdx.x;
    const int i   = blockIdx.x * 256 + tid;
    const int j0  = blockIdx.y * TCHUNK;
    const float ls   = lengthscale[0];
    const float inv2 = 1.0f / (ls * ls);
    for (int jj = tid; jj < TCHUNK; jj += 256) {
        const float4* tr = reinterpret_cast<const float4*>(train_X + (size_t)(j0 + jj) * DIM);
        float s = 0.f;
        #pragma unroll
        for (int k = 0; k < DIM / 4; ++k) {
            float4 t = tr[k];
            s += t.x * t.x + t.y * t.y + t.z * t.z + t.w * t.w;
        }
        nt_lds[jj] = s * inv2;
        al_lds[jj] = alphas[j0 + jj];
    }
    __syncthreads();
    float xr[DIM]; float nxv = 0.f;
    {
        const float4* xp = reinterpret_cast<const float4*>(test_X + (size_t)i * DIM);
        #pragma unroll
        for (int k = 0; k < DIM / 4; ++k) {
            float4 v = xp[k];
            xr[4*k+0] = v.x; xr[4*k+1] = v.y; xr[4*k+2] = v.z; xr[4*k+3] = v.w;
            nxv += v.x*v.x + v.y*v.y + v.z*v.z + v.w*v.w;
        }
        nxv *= inv2;
        #pragma unroll
        for (int k = 0; k < DIM; ++k) xr[k] *= inv2;
    }
    float acc = 0.f;
    for (int jj = 0; jj < TCHUNK; ++jj) {
        const float* trow = train_X + (size_t)(j0 + jj) * DIM;
        float d0 = 0.f, d1 = 0.f, d2 = 0.f, d3 = 0.f;
        #pragma unroll
        for (int k4 = 0; k4 < DIM / 4; ++k4) {
            float4 t = reinterpret_cast<const float4*>(trow)[k4];
            d0 = fmaf(xr[4*k4+0], t.x, d0);
            d1 = fmaf(xr[4*k4+1], t.y, d1);
            d2 = fmaf(xr[4*k4+2], t.z, d2);
            d3 = fmaf(xr[4*k4+3], t.w, d3);
        }
        float dot = (d0 + d1) + (d2 + d3);
        float sq  = nxv + nt_lds[jj] - 2.0f * dot;
        sq = fmaxf(sq, 0.0f);
        acc = fmaf(__expf(-0.5f * sq), al_lds[jj], acc);
    }
    atomicAdd(&out[i], acc);
}

extern "C" void kernel_launch(void* const* d_in, const int* in_sizes, int n_in,
                              void* d_out, int out_size, void* d_ws, size_t ws_size,
                              hipStream_t stream) {
    const float* test_X      = (const float*)d_in[0];
    const float* train_X     = (const float*)d_in[1];
    const float* alphas      = (const float*)d_in[2];
    const float* lengthscale = (const float*)d_in[3];
    float* out = (float*)d_out;

    hipMemsetAsync(out, 0, NTEST * sizeof(float), stream);

    const size_t need = (size_t)(NTEST + NTRAIN) * DIM * sizeof(_Float16)
                      + (NTEST + NTRAIN) * sizeof(float);
    if (ws_size >= need) {
        _Float16* A_hi = (_Float16*)d_ws;
        _Float16* B_hi = A_hi + (size_t)NTEST * DIM;
        float*    nx2  = (float*)(B_hi + (size_t)NTRAIN * DIM);
        float*    wtp  = nx2 + NTEST;

        krr_prep<<<(NTEST + NTRAIN) / 4, 256, 0, stream>>>(
            test_X, train_X, alphas, lengthscale, A_hi, B_hi, nx2, wtp);

        dim3 grid(NTEST / 256, NCOLSPLIT);
        krr_mfma<<<grid, 64 * WPB, 0, stream>>>(A_hi, B_hi, nx2, wtp,
                                                lengthscale, out);
    } else {
        dim3 grid(NTEST / 256, NCHUNK);
        krr_main<<<grid, 256, 0, stream>>>(test_X, train_X, alphas, lengthscale, out);
    }
}